// Round 9
// baseline (66.816 us; speedup 1.0000x reference)
//
#include <hip/hip_runtime.h>

#define DIMK 128

typedef __bf16 bf16x8 __attribute__((ext_vector_type(8)));
typedef float  f32x4  __attribute__((ext_vector_type(4)));

// ---- helpers ---------------------------------------------------------------
__device__ inline unsigned short f32_to_bf16_rne(float f) {
    unsigned u = __float_as_uint(f);
    u += 0x7FFFu + ((u >> 16) & 1u);      // round-to-nearest-even
    return (unsigned short)(u >> 16);
}

// Fragment-pack layout for a 16-row tile:
//   ushort offset = tile*2048 + kk*512 + (kb*16 + col)*8 + j
// for element [tile*16+col][kk*32 + kb*8 + j]; per-lane (lane = kb*16+col)
// a fragment load is  base + kk*512 + lane*8  -> 16B contiguous per lane.

// ---- kernel 1: pack fp32 rows -> scaled bf16 fragment tiles + row norms ----
__global__ void pack_rows(const float* __restrict__ src,
                          unsigned short* __restrict__ dst,
                          float* __restrict__ norm2,
                          int n_valid, int n_rows_pad, float scale) {
    int wave = threadIdx.x >> 6, lane = threadIdx.x & 63;
    int row = blockIdx.x * 4 + wave;
    if (row >= n_rows_pad) return;
    int srow = min(row, n_valid - 1);
    int e = lane * 2;
    float2 v = *(const float2*)(src + (size_t)srow * DIMK + e);
    unsigned pk = (unsigned)f32_to_bf16_rne(scale * v.x) |
                  ((unsigned)f32_to_bf16_rne(scale * v.y) << 16);
    int tile = row >> 4, col = row & 15;
    int kk = e >> 5, kb = (e >> 3) & 3, j = e & 7;
    size_t off = (size_t)tile * 2048 + kk * 512 + (kb * 16 + col) * 8 + j;
    *(unsigned*)(dst + off) = pk;           // j even -> dword aligned
    float s = v.x * v.x + v.y * v.y;        // norms from UNscaled values
#pragma unroll
    for (int o = 1; o < 64; o <<= 1) s += __shfl_xor(s, o, 64);
    if (lane == 0) norm2[row] = s;
}

// ---- kernel 2: segment counts -> per-position weight array (SoA) -----------
__global__ void seg_weights(const int* __restrict__ ids,
                            const int* __restrict__ nseg_p,
                            float* __restrict__ wsa, int n_pos) {
    __shared__ int   cnt[256];
    __shared__ float w[256];
    int nseg = nseg_p[0];
    if (nseg > 256) nseg = 256;
    int t = threadIdx.x;
    if (t < nseg) cnt[t] = 0;
    __syncthreads();
    for (int p = t; p < n_pos; p += blockDim.x) atomicAdd(&cnt[ids[p]], 1);
    __syncthreads();
    if (t < nseg) w[t] = 1.0f / ((float)nseg * (float)max(cnt[t], 1));
    __syncthreads();
    for (int p = t; p < n_pos; p += blockDim.x) wsa[p] = w[ids[p]];
}

// ---- kernel 3: fused cross-GEMM + sqrt + weighted reduce -------------------
// Block: 4 waves x 64 nodes = 256 nodes, 16 position-tiles (256 positions),
// double-buffered 4-tile chunks, counted vmcnt(4) + raw barriers (6/block).
// Accumulator initialized with t2+p2 (MFMA C-in is a free adder); target
// packed with scale -2, so d = t2 + p2 - 2*cross = squared distance.
__global__ __launch_bounds__(256, 4)
void l2dist_main(const unsigned short* __restrict__ pb,   // packed bf16 pred
                 const float* __restrict__ p2,
                 const unsigned short* __restrict__ tb,   // packed bf16(-2*t)
                 const float* __restrict__ t2g,
                 const float* __restrict__ wg,
                 float* __restrict__ out,
                 int n_nodes) {
    __shared__ __align__(16) unsigned short lbuf[2][8192];  // 2 x 16KB (4 tiles)
    __shared__ __align__(16) float t2_lds[256];
    __shared__ __align__(16) float w_lds[256];

    const int tid  = threadIdx.x;
    const int lane = tid & 63;
    const int wave = tid >> 6;
    const int col  = lane & 15;
    const int kb   = lane >> 4;
    const int n0   = blockIdx.y * 256 + wave * 64;
    const int tbase = blockIdx.x * 16;       // 16 tiles per block
    const int rbase = tbase * 16;            // 256 positions per block

    // ---- B fragments: 4 node groups, loaded ONCE per block ----
    bf16x8 bfrag[4][4];
    float p2g[4];
    const unsigned short* bp = pb + ((size_t)(n0 >> 4)) * 2048 + (size_t)lane * 8;
#pragma unroll
    for (int g = 0; g < 4; ++g) {
#pragma unroll
        for (int kk = 0; kk < 4; ++kk)
            bfrag[g][kk] = *(const bf16x8*)(bp + g * 2048 + kk * 512);
        p2g[g] = p2[n0 + g * 16 + col];
    }

    // ---- stage t2/w slices (width-4, each wave a 64-float quarter) ----
    __builtin_amdgcn_global_load_lds(
        (const __attribute__((address_space(1))) unsigned int*)(const void*)
            (t2g + rbase + wave * 64 + lane),
        (__attribute__((address_space(3))) unsigned int*)(void*)
            (&t2_lds[wave * 64]), 4, 0, 0);
    __builtin_amdgcn_global_load_lds(
        (const __attribute__((address_space(1))) unsigned int*)(const void*)
            (wg + rbase + wave * 64 + lane),
        (__attribute__((address_space(3))) unsigned int*)(void*)
            (&w_lds[wave * 64]), 4, 0, 0);

    // ---- chunk staging: 4 tiles, each wave its 1KB quarter, linear ----
    const unsigned short* sgp = tb + (size_t)tbase * 2048 + wave * 512 + lane * 8;
#define STAGE(C, B)                                                            \
    _Pragma("unroll")                                                          \
    for (int t_ = 0; t_ < 4; ++t_) {                                           \
        __builtin_amdgcn_global_load_lds(                                      \
            (const __attribute__((address_space(1))) unsigned int*)(const void*)\
                (sgp + ((C) * 4 + t_) * 2048),                                 \
            (__attribute__((address_space(3))) unsigned int*)(void*)           \
                (&lbuf[B][t_ * 2048] + wave * 512),                            \
            16, 0, 0);                                                         \
    }

    STAGE(0, 0);
    STAGE(1, 1);

    float acc0 = 0.f, acc1 = 0.f, acc2 = 0.f, acc3 = 0.f;

#pragma unroll
    for (int c = 0; c < 4; ++c) {
        // chunk c resident in buf[c&1]; chunk c+1 (if any) still in flight
        if (c < 3) { asm volatile("s_waitcnt vmcnt(4)" ::: "memory"); }
        else       { asm volatile("s_waitcnt vmcnt(0)" ::: "memory"); }
        __builtin_amdgcn_s_barrier();       // all waves' quarters landed

#pragma unroll
        for (int t = 0; t < 4; ++t) {
            const unsigned short* rb = &lbuf[c & 1][t * 2048] + lane * 8;
            bf16x8 a0 = *(const bf16x8*)(rb);
            bf16x8 a1 = *(const bf16x8*)(rb + 512);
            bf16x8 a2 = *(const bf16x8*)(rb + 1024);
            bf16x8 a3 = *(const bf16x8*)(rb + 1536);

            f32x4 t2v = *(const f32x4*)&t2_lds[(c * 4 + t) * 16 + kb * 4];
            f32x4 wv  = *(const f32x4*)&w_lds[(c * 4 + t) * 16 + kb * 4];

            f32x4 d0 = t2v + p2g[0];        // C-init = t2 + p2
            f32x4 d1 = t2v + p2g[1];
            f32x4 d2 = t2v + p2g[2];
            f32x4 d3 = t2v + p2g[3];
            d0 = __builtin_amdgcn_mfma_f32_16x16x32_bf16(a0, bfrag[0][0], d0, 0, 0, 0);
            d1 = __builtin_amdgcn_mfma_f32_16x16x32_bf16(a0, bfrag[1][0], d1, 0, 0, 0);
            d2 = __builtin_amdgcn_mfma_f32_16x16x32_bf16(a0, bfrag[2][0], d2, 0, 0, 0);
            d3 = __builtin_amdgcn_mfma_f32_16x16x32_bf16(a0, bfrag[3][0], d3, 0, 0, 0);
            d0 = __builtin_amdgcn_mfma_f32_16x16x32_bf16(a1, bfrag[0][1], d0, 0, 0, 0);
            d1 = __builtin_amdgcn_mfma_f32_16x16x32_bf16(a1, bfrag[1][1], d1, 0, 0, 0);
            d2 = __builtin_amdgcn_mfma_f32_16x16x32_bf16(a1, bfrag[2][1], d2, 0, 0, 0);
            d3 = __builtin_amdgcn_mfma_f32_16x16x32_bf16(a1, bfrag[3][1], d3, 0, 0, 0);
            d0 = __builtin_amdgcn_mfma_f32_16x16x32_bf16(a2, bfrag[0][2], d0, 0, 0, 0);
            d1 = __builtin_amdgcn_mfma_f32_16x16x32_bf16(a2, bfrag[1][2], d1, 0, 0, 0);
            d2 = __builtin_amdgcn_mfma_f32_16x16x32_bf16(a2, bfrag[2][2], d2, 0, 0, 0);
            d3 = __builtin_amdgcn_mfma_f32_16x16x32_bf16(a2, bfrag[3][2], d3, 0, 0, 0);
            d0 = __builtin_amdgcn_mfma_f32_16x16x32_bf16(a3, bfrag[0][3], d0, 0, 0, 0);
            d1 = __builtin_amdgcn_mfma_f32_16x16x32_bf16(a3, bfrag[1][3], d1, 0, 0, 0);
            d2 = __builtin_amdgcn_mfma_f32_16x16x32_bf16(a3, bfrag[2][3], d2, 0, 0, 0);
            d3 = __builtin_amdgcn_mfma_f32_16x16x32_bf16(a3, bfrag[3][3], d3, 0, 0, 0);

#pragma unroll
            for (int j = 0; j < 4; ++j) {
                acc0 = fmaf(wv[j], __builtin_amdgcn_sqrtf(fmaxf(d0[j], 0.f)), acc0);
                acc1 = fmaf(wv[j], __builtin_amdgcn_sqrtf(fmaxf(d1[j], 0.f)), acc1);
                acc2 = fmaf(wv[j], __builtin_amdgcn_sqrtf(fmaxf(d2[j], 0.f)), acc2);
                acc3 = fmaf(wv[j], __builtin_amdgcn_sqrtf(fmaxf(d3[j], 0.f)), acc3);
            }
        }

        if (c < 2) {
            __builtin_amdgcn_s_barrier();   // all waves done reading buf[c&1]
            STAGE(c + 2, c & 1);            // refill it with chunk c+2
        }
    }
#undef STAGE

    // reduce over the 4 kb lane-groups -> per-node totals
    acc0 += __shfl_xor(acc0, 16, 64);  acc0 += __shfl_xor(acc0, 32, 64);
    acc1 += __shfl_xor(acc1, 16, 64);  acc1 += __shfl_xor(acc1, 32, 64);
    acc2 += __shfl_xor(acc2, 16, 64);  acc2 += __shfl_xor(acc2, 32, 64);
    acc3 += __shfl_xor(acc3, 16, 64);  acc3 += __shfl_xor(acc3, 32, 64);
    if (lane < 16) {
        int na = n0 + col;
        if (na      < n_nodes) atomicAdd(out + na,      acc0);
        if (na + 16 < n_nodes) atomicAdd(out + na + 16, acc1);
        if (na + 32 < n_nodes) atomicAdd(out + na + 32, acc2);
        if (na + 48 < n_nodes) atomicAdd(out + na + 48, acc3);
    }
}

// ---- launcher --------------------------------------------------------------
extern "C" void kernel_launch(void* const* d_in, const int* in_sizes, int n_in,
                              void* d_out, int out_size, void* d_ws, size_t ws_size,
                              hipStream_t stream) {
    const float* pred  = (const float*)d_in[0];
    const float* tgt   = (const float*)d_in[1];
    const int*   ids   = (const int*)d_in[2];
    const int*   nsegp = (const int*)d_in[3];
    float* out = (float*)d_out;

    int n_nodes = in_sizes[0] / DIMK;
    int n_pos   = in_sizes[2];

    int gy = (n_nodes + 255) / 256;          // node panels (256 nodes each)
    int n_rows_pad = gy * 256;

    char* ws = (char*)d_ws;
    size_t off_pb = 0;                                        // packed pred bf16
    size_t off_tb = off_pb + (size_t)n_rows_pad * DIMK * 2;   // packed -2*target
    size_t off_p2 = off_tb + (size_t)n_pos * DIMK * 2;        // pred norms
    size_t off_t2 = off_p2 + (size_t)n_rows_pad * 4;          // target norms
    size_t off_w  = off_t2 + (size_t)n_pos * 4;               // weights
    unsigned short* pb  = (unsigned short*)(ws + off_pb);
    unsigned short* tb  = (unsigned short*)(ws + off_tb);
    float*          p2  = (float*)(ws + off_p2);
    float*          t2  = (float*)(ws + off_t2);
    float*          wsa = (float*)(ws + off_w);

    pack_rows<<<(n_rows_pad + 3) / 4, 256, 0, stream>>>(pred, pb, p2, n_nodes, n_rows_pad, 1.0f);
    pack_rows<<<(n_pos + 3) / 4, 256, 0, stream>>>(tgt, tb, t2, n_pos, n_pos, -2.0f);
    seg_weights<<<1, 1024, 0, stream>>>(ids, nsegp, wsa, n_pos);
    hipMemsetAsync(out, 0, (size_t)out_size * sizeof(float), stream);

    dim3 grid(n_pos / 256, gy);              // x = 8 position ranges (fast)
    l2dist_main<<<grid, 256, 0, stream>>>(pb, p2, tb, t2, wsa, out, n_nodes);
}

// Round 12
// 57.218 us; speedup vs baseline: 1.1677x; 1.1677x over previous
//
#include <hip/hip_runtime.h>

#define DIMK 128
#define POS_PER_BLOCK 512
#define NCHUNK 8            // 8 chunks x 4 tiles x 16 pos = 512
#define NODES_PER_BLOCK 128

typedef __bf16 bf16x8 __attribute__((ext_vector_type(8)));
typedef float  f32x4  __attribute__((ext_vector_type(4)));

// ---- helpers ---------------------------------------------------------------
__device__ inline unsigned short f32_to_bf16_rne(float f) {
    unsigned u = __float_as_uint(f);
    u += 0x7FFFu + ((u >> 16) & 1u);      // round-to-nearest-even
    return (unsigned short)(u >> 16);
}

// Fragment-pack layout for a 16-row tile (= 2048 ushorts = 4KB):
//   ushort offset = tile*2048 + kk*512 + (kb*16 + col)*8 + j
// per-lane (lane = kb*16+col) a fragment load is base + kk*512 + lane*8.

// ---- kernel 1: pack fp32 rows -> scaled bf16 fragment tiles + row norms ----
__global__ void pack_rows(const float* __restrict__ src,
                          unsigned short* __restrict__ dst,
                          float* __restrict__ norm2,
                          int n_valid, int n_rows_pad, float scale) {
    int wave = threadIdx.x >> 6, lane = threadIdx.x & 63;
    int row = blockIdx.x * 4 + wave;
    if (row >= n_rows_pad) return;
    int srow = min(row, n_valid - 1);
    int e = lane * 2;
    float2 v = *(const float2*)(src + (size_t)srow * DIMK + e);
    unsigned pk = (unsigned)f32_to_bf16_rne(scale * v.x) |
                  ((unsigned)f32_to_bf16_rne(scale * v.y) << 16);
    int tile = row >> 4, col = row & 15;
    int kk = e >> 5, kb = (e >> 3) & 3, j = e & 7;
    size_t off = (size_t)tile * 2048 + kk * 512 + (kb * 16 + col) * 8 + j;
    *(unsigned*)(dst + off) = pk;           // j even -> dword aligned
    float s = v.x * v.x + v.y * v.y;        // norms from UNscaled values
#pragma unroll
    for (int o = 1; o < 64; o <<= 1) s += __shfl_xor(s, o, 64);
    if (lane == 0) norm2[row] = s;
}

// ---- kernel 2: segment counts -> per-position weight array (SoA) -----------
__global__ void seg_weights(const int* __restrict__ ids,
                            const int* __restrict__ nseg_p,
                            float* __restrict__ wsa, int n_pos) {
    __shared__ int   cnt[256];
    __shared__ float w[256];
    int nseg = nseg_p[0];
    if (nseg > 256) nseg = 256;
    int t = threadIdx.x;
    if (t < nseg) cnt[t] = 0;
    __syncthreads();
    for (int p = t; p < n_pos; p += blockDim.x) atomicAdd(&cnt[ids[p]], 1);
    __syncthreads();
    if (t < nseg) w[t] = 1.0f / ((float)nseg * (float)max(cnt[t], 1));
    __syncthreads();
    for (int p = t; p < n_pos; p += blockDim.x) wsa[p] = w[ids[p]];
}

// ---- kernel 3: fused cross-GEMM + sqrt + weighted reduce -------------------
// 4 waves x 32 nodes = 128 nodes/block, 512 positions/block (32 tiles).
// Chunked double-buffer: chunk = 4 tiles = 16KB (tile stride 2048 ushorts!).
// Stage chunk c+2 while computing c; counted vmcnt(4); raw barriers only.
// Accumulator C-init = t2+p2; target packed with scale -2 so d = sq-distance.
__global__ __launch_bounds__(256, 4)
void l2dist_main(const unsigned short* __restrict__ pb,   // packed bf16 pred
                 const float* __restrict__ p2,
                 const unsigned short* __restrict__ tb,   // packed bf16(-2*t)
                 const float* __restrict__ t2g,
                 const float* __restrict__ wg,
                 float* __restrict__ out,
                 int n_nodes) {
    __shared__ __align__(16) unsigned short lbuf[2][8192];   // 2 x 16KB chunks
    __shared__ __align__(16) float t2_lds[POS_PER_BLOCK];
    __shared__ __align__(16) float w_lds[POS_PER_BLOCK];

    const int tid  = threadIdx.x;
    const int lane = tid & 63;
    const int wave = tid >> 6;
    const int col  = lane & 15;
    const int kb   = lane >> 4;
    const int n0   = blockIdx.y * NODES_PER_BLOCK + wave * 32;
    const int tbase = blockIdx.x * (POS_PER_BLOCK / 16);   // first tile
    const int rbase = blockIdx.x * POS_PER_BLOCK;          // first position

    // ---- B fragments (2 node groups) + norms ----
    bf16x8 bfrag[2][4];
    float p2g[2];
    const unsigned short* bp = pb + ((size_t)(n0 >> 4)) * 2048 + (size_t)lane * 8;
#pragma unroll
    for (int g = 0; g < 2; ++g) {
#pragma unroll
        for (int kk = 0; kk < 4; ++kk)
            bfrag[g][kk] = *(const bf16x8*)(bp + g * 2048 + kk * 512);
        p2g[g] = p2[n0 + g * 16 + col];
    }

    // ---- t2 / w -> LDS (plain loads + ds_write; before any stage issue) ----
    t2_lds[tid]       = t2g[rbase + tid];
    t2_lds[tid + 256] = t2g[rbase + tid + 256];
    w_lds[tid]        = wg[rbase + tid];
    w_lds[tid + 256]  = wg[rbase + tid + 256];

    // ---- chunk staging (all loop VMEM is global_load_lds) ----
    const unsigned short* sgp = tb + (size_t)tbase * 2048 + wave * 512 + lane * 8;
#define STAGE(C)                                                               \
    _Pragma("unroll")                                                          \
    for (int t_ = 0; t_ < 4; ++t_) {                                           \
        __builtin_amdgcn_global_load_lds(                                      \
            (const __attribute__((address_space(1))) unsigned int*)(const void*)\
                (sgp + (size_t)((C) * 4 + t_) * 2048),                         \
            (__attribute__((address_space(3))) unsigned int*)(void*)           \
                (&lbuf[(C) & 1][t_ * 2048] + wave * 512),                      \
            16, 0, 0);                                                         \
    }

    STAGE(0);
    STAGE(1);

    // publish t2/w LDS writes to the block (stages NOT drained)
    asm volatile("s_waitcnt lgkmcnt(0)" ::: "memory");
    __builtin_amdgcn_s_barrier();

    float acc0 = 0.f, acc1 = 0.f;

#pragma unroll
    for (int c = 0; c < NCHUNK; ++c) {
        // chunk c landed when <= 4 stage-loads outstanding (chunk c+1's)
        if (c < NCHUNK - 1) { asm volatile("s_waitcnt vmcnt(4)" ::: "memory"); }
        else                { asm volatile("s_waitcnt vmcnt(0)" ::: "memory"); }
        __builtin_amdgcn_s_barrier();       // every wave's quarter landed

        __builtin_amdgcn_s_setprio(1);
#pragma unroll
        for (int t = 0; t < 4; ++t) {
            const unsigned short* rb = &lbuf[c & 1][t * 2048] + lane * 8;
            bf16x8 a0 = *(const bf16x8*)(rb);
            bf16x8 a1 = *(const bf16x8*)(rb + 512);
            bf16x8 a2 = *(const bf16x8*)(rb + 1024);
            bf16x8 a3 = *(const bf16x8*)(rb + 1536);

            int pr = (c * 4 + t) * 16 + kb * 4;
            f32x4 t2v = *(const f32x4*)&t2_lds[pr];
            f32x4 wv  = *(const f32x4*)&w_lds[pr];

            f32x4 d0 = t2v + p2g[0];        // C-init = t2 + p2
            f32x4 d1 = t2v + p2g[1];
            d0 = __builtin_amdgcn_mfma_f32_16x16x32_bf16(a0, bfrag[0][0], d0, 0, 0, 0);
            d1 = __builtin_amdgcn_mfma_f32_16x16x32_bf16(a0, bfrag[1][0], d1, 0, 0, 0);
            d0 = __builtin_amdgcn_mfma_f32_16x16x32_bf16(a1, bfrag[0][1], d0, 0, 0, 0);
            d1 = __builtin_amdgcn_mfma_f32_16x16x32_bf16(a1, bfrag[1][1], d1, 0, 0, 0);
            d0 = __builtin_amdgcn_mfma_f32_16x16x32_bf16(a2, bfrag[0][2], d0, 0, 0, 0);
            d1 = __builtin_amdgcn_mfma_f32_16x16x32_bf16(a2, bfrag[1][2], d1, 0, 0, 0);
            d0 = __builtin_amdgcn_mfma_f32_16x16x32_bf16(a3, bfrag[0][3], d0, 0, 0, 0);
            d1 = __builtin_amdgcn_mfma_f32_16x16x32_bf16(a3, bfrag[1][3], d1, 0, 0, 0);

#pragma unroll
            for (int j = 0; j < 4; ++j) {
                acc0 = fmaf(wv[j], __builtin_amdgcn_sqrtf(fmaxf(d0[j], 0.f)), acc0);
                acc1 = fmaf(wv[j], __builtin_amdgcn_sqrtf(fmaxf(d1[j], 0.f)), acc1);
            }
        }
        __builtin_amdgcn_s_setprio(0);

        if (c + 2 < NCHUNK) {
            __builtin_amdgcn_s_barrier();   // all waves done reading buf[c&1]
            STAGE(c + 2);                   // refill it with chunk c+2
        }
    }
#undef STAGE

    // reduce over the 4 kb lane-groups -> per-node totals
    acc0 += __shfl_xor(acc0, 16, 64);  acc0 += __shfl_xor(acc0, 32, 64);
    acc1 += __shfl_xor(acc1, 16, 64);  acc1 += __shfl_xor(acc1, 32, 64);
    if (lane < 16) {
        int na = n0 + col;
        if (na      < n_nodes) atomicAdd(out + na,      acc0);
        if (na + 16 < n_nodes) atomicAdd(out + na + 16, acc1);
    }
}

// ---- launcher --------------------------------------------------------------
extern "C" void kernel_launch(void* const* d_in, const int* in_sizes, int n_in,
                              void* d_out, int out_size, void* d_ws, size_t ws_size,
                              hipStream_t stream) {
    const float* pred  = (const float*)d_in[0];
    const float* tgt   = (const float*)d_in[1];
    const int*   ids   = (const int*)d_in[2];
    const int*   nsegp = (const int*)d_in[3];
    float* out = (float*)d_out;

    int n_nodes = in_sizes[0] / DIMK;
    int n_pos   = in_sizes[2];

    int gy = (n_nodes + NODES_PER_BLOCK - 1) / NODES_PER_BLOCK;
    int n_rows_pad = gy * NODES_PER_BLOCK;

    char* ws = (char*)d_ws;
    size_t off_pb = 0;                                        // packed pred bf16
    size_t off_tb = off_pb + (size_t)n_rows_pad * DIMK * 2;   // packed -2*target
    size_t off_p2 = off_tb + (size_t)n_pos * DIMK * 2;        // pred norms
    size_t off_t2 = off_p2 + (size_t)n_rows_pad * 4;          // target norms
    size_t off_w  = off_t2 + (size_t)n_pos * 4;               // weights
    unsigned short* pb  = (unsigned short*)(ws + off_pb);
    unsigned short* tb  = (unsigned short*)(ws + off_tb);
    float*          p2  = (float*)(ws + off_p2);
    float*          t2  = (float*)(ws + off_t2);
    float*          wsa = (float*)(ws + off_w);

    pack_rows<<<(n_rows_pad + 3) / 4, 256, 0, stream>>>(pred, pb, p2, n_nodes, n_rows_pad, 1.0f);
    pack_rows<<<(n_pos + 3) / 4, 256, 0, stream>>>(tgt, tb, t2, n_pos, n_pos, -2.0f);
    seg_weights<<<1, 1024, 0, stream>>>(ids, nsegp, wsa, n_pos);
    hipMemsetAsync(out, 0, (size_t)out_size * sizeof(float), stream);

    dim3 grid(n_pos / POS_PER_BLOCK, gy);    // (4, 392) position-fast
    l2dist_main<<<grid, 256, 0, stream>>>(pb, p2, tb, t2, wsa, out, n_nodes);
}